// Round 1
// baseline (52.514 us; speedup 1.0000x reference)
//
#include <hip/hip_runtime.h>
#include <stdint.h>

#define IN_F 8192
#define OUT_F 8192
#define BATCH 8
#define XWORDS (BATCH * IN_F / 32)  // 2048 packed sign words (8 KB)

// Pack the sign bits of x[8][8192] into xbits[2048] (bit i of word w = signbit
// of flat element w*32+i). Uses wave ballot: 64 lanes -> 2 words.
__global__ void pack_sign_kernel(const uint32_t* __restrict__ x,
                                 uint32_t* __restrict__ xbits) {
  int i = blockIdx.x * blockDim.x + threadIdx.x;  // 0 .. 65535
  uint32_t neg = x[i] >> 31;
  unsigned long long m = __ballot(neg != 0);
  int lane = threadIdx.x & 63;
  if (lane == 0) {
    int w = i >> 5;  // even (i is a multiple of 64 here)
    xbits[w] = (uint32_t)m;
    xbits[w + 1] = (uint32_t)(m >> 32);
  }
}

// One wave per output row. Lane streams the fp32 weight row as uint4,
// extracts 4 sign bits, and accumulates popcount(wsign ^ xsign) per batch.
// out[b,o] = IN_F - 2*mismatch + bias[o].
__global__ __launch_bounds__(256) void ternary_gemv_kernel(
    const uint4* __restrict__ W, const uint32_t* __restrict__ xbits,
    const float* __restrict__ bias, float* __restrict__ out) {
  __shared__ uint32_t xlds[XWORDS];
  for (int i = threadIdx.x; i < XWORDS; i += 256) xlds[i] = xbits[i];
  __syncthreads();

  const int warp = threadIdx.x >> 6;
  const int lane = threadIdx.x & 63;
  const int row = blockIdx.x * 4 + warp;
  const uint4* wrow = W + (size_t)row * (IN_F / 4);

  int cnt[BATCH] = {0, 0, 0, 0, 0, 0, 0, 0};
  const int shift = (lane & 7) * 4;  // bit offset of this lane's nibble
  const int wb = lane >> 3;          // which of the 8 words this iter touches

  // 32 iterations: wave covers it*256 .. it*256+255 elements of the row.
  // Lane's 4 elements are at pos = it*256 + lane*4  -> word it*8 + lane/8,
  // nibble shift (lane&7)*4 (iteration-invariant).
#pragma unroll 4
  for (int it = 0; it < 32; ++it) {
    uint4 u = wrow[it * 64 + lane];
    uint32_t wn = (u.x >> 31) | ((u.y >> 31) << 1) |
                  ((u.z >> 31) << 2) | ((u.w >> 31) << 3);
    const int widx = it * 8 + wb;
#pragma unroll
    for (int b = 0; b < BATCH; ++b) {
      uint32_t xn = (xlds[b * 256 + widx] >> shift) & 0xFu;
      cnt[b] += __popc(wn ^ xn);
    }
  }

  // Wave-level reduce of the 8 mismatch counts.
#pragma unroll
  for (int b = 0; b < BATCH; ++b) {
#pragma unroll
    for (int off = 32; off > 0; off >>= 1)
      cnt[b] += __shfl_down(cnt[b], off);
  }

  if (lane == 0) {
    float bv = bias[row];
#pragma unroll
    for (int b = 0; b < BATCH; ++b)
      out[(size_t)b * OUT_F + row] = (float)(IN_F - 2 * cnt[b]) + bv;
  }
}

extern "C" void kernel_launch(void* const* d_in, const int* in_sizes, int n_in,
                              void* d_out, int out_size, void* d_ws, size_t ws_size,
                              hipStream_t stream) {
  const uint32_t* x = (const uint32_t*)d_in[0];  // fp32 bits of input [8,8192]
  const uint4* W = (const uint4*)d_in[1];        // fp32 bits of weight [8192,8192]
  const float* bias = (const float*)d_in[2];     // [8192]
  float* out = (float*)d_out;                    // [8,8192]
  uint32_t* xbits = (uint32_t*)d_ws;             // 8 KB packed sign bits

  pack_sign_kernel<<<(BATCH * IN_F) / 256, 256, 0, stream>>>(x, xbits);
  ternary_gemv_kernel<<<OUT_F / 4, 256, 0, stream>>>(W, xbits, bias, out);
}

// Round 3
// 50.996 us; speedup vs baseline: 1.0298x; 1.0298x over previous
//
#include <hip/hip_runtime.h>
#include <stdint.h>

#define IN_F 8192
#define OUT_F 8192
#define BATCH 8
// Permuted x sign-bit layout, matched to the gemv's lane order:
//   word[(b*4 + m)*64 + l], bit (4*i + k) = signbit(x[b*8192 + m*2048 + i*256 + l*4 + k])
#define XPW (BATCH * 4 * 64)  // 2048 words = 8 KB

typedef unsigned int u32x4 __attribute__((ext_vector_type(4)));

__global__ __launch_bounds__(256) void pack_sign_perm(
    const u32x4* __restrict__ x, uint32_t* __restrict__ xp) {
  const int t = blockIdx.x * 256 + threadIdx.x;  // 0..2047
  const int b = t >> 8;
  const int m = (t >> 6) & 3;
  const int l = t & 63;
  const u32x4* base = x + (b * IN_F + m * 2048 + l * 4) / 4;
  uint32_t w = 0;
#pragma unroll
  for (int i = 0; i < 8; ++i) {
    u32x4 u = base[i * 64];
    uint32_t nib = (u.x >> 31) | ((u.y >> 31) << 1) |
                   ((u.z >> 31) << 2) | ((u.w >> 31) << 3);
    w |= nib << (4 * i);
  }
  xp[t] = w;
}

// One wave per output row. Each lane builds 32 weight sign bits per 8-KB
// macro-tile (8 nontemporal uint4 loads), then per batch: xor + popcount
// against the pre-permuted x word (v_xor + v_bcnt accumulate).
__global__ __launch_bounds__(256) void ternary_gemv2(
    const u32x4* __restrict__ W, const uint32_t* __restrict__ xp,
    const float* __restrict__ bias, float* __restrict__ out) {
  __shared__ uint32_t xl[XPW];
  for (int i = threadIdx.x; i < XPW; i += 256) xl[i] = xp[i];
  __syncthreads();

  const int warp = threadIdx.x >> 6;
  const int lane = threadIdx.x & 63;
  const int row = blockIdx.x * 4 + warp;
  const u32x4* wrow = W + (size_t)row * (IN_F / 4);

  int cnt[BATCH] = {0, 0, 0, 0, 0, 0, 0, 0};

#pragma unroll
  for (int m = 0; m < 4; ++m) {
    u32x4 u[8];
#pragma unroll
    for (int i = 0; i < 8; ++i)
      u[i] = __builtin_nontemporal_load(&wrow[m * 512 + i * 64 + lane]);

    uint32_t wn = 0;
#pragma unroll
    for (int i = 0; i < 8; ++i) {
      uint32_t nib = (u[i].x >> 31) | ((u[i].y >> 31) << 1) |
                     ((u[i].z >> 31) << 2) | ((u[i].w >> 31) << 3);
      wn |= nib << (4 * i);
    }

#pragma unroll
    for (int b = 0; b < BATCH; ++b)
      cnt[b] += __popc(wn ^ xl[(b * 4 + m) * 64 + lane]);
  }

  // Wave-level reduce of the 8 mismatch counts.
#pragma unroll
  for (int b = 0; b < BATCH; ++b) {
#pragma unroll
    for (int off = 32; off > 0; off >>= 1)
      cnt[b] += __shfl_down(cnt[b], off);
  }

  if (lane == 0) {
    const float bv = bias[row];
#pragma unroll
    for (int b = 0; b < BATCH; ++b)
      out[(size_t)b * OUT_F + row] = (float)(IN_F - 2 * cnt[b]) + bv;
  }
}

extern "C" void kernel_launch(void* const* d_in, const int* in_sizes, int n_in,
                              void* d_out, int out_size, void* d_ws, size_t ws_size,
                              hipStream_t stream) {
  const u32x4* x = (const u32x4*)d_in[0];        // fp32 bits of input [8,8192]
  const u32x4* W = (const u32x4*)d_in[1];        // fp32 bits of weight [8192,8192]
  const float* bias = (const float*)d_in[2];     // [8192]
  float* out = (float*)d_out;                    // [8,8192]
  uint32_t* xp = (uint32_t*)d_ws;                // 8 KB permuted sign bits

  pack_sign_perm<<<XPW / 256, 256, 0, stream>>>(x, xp);
  ternary_gemv2<<<OUT_F / 4, 256, 0, stream>>>(W, xp, bias, out);
}